// Round 1
// baseline (246.905 us; speedup 1.0000x reference)
//
#include <hip/hip_runtime.h>
#include <hip/hip_bf16.h>
#include <math.h>

// Self-attention, N=8192, D_in=256, D_out=128, fp32 in/out.
// Strategy: fp32-accurate via bf16 hi/lo split (3 MFMAs per logical fp32 GEMM),
// flash attention with KV-split=4 (flash-decoding) + merge pass.
// ws layout: Qh,Ql,Kh,Kl,VTh,VTl (6 x 2MB bf16) | Opart (4 x 4MB f32) | mpart,lpart.

typedef float f32x4 __attribute__((ext_vector_type(4)));
typedef __bf16 bf16x8 __attribute__((ext_vector_type(8)));

#define N_TOK 8192
#define D_INN 256
#define D_OUTT 128
#define NSPLIT 4
#define NSTEP 32  // (8192/4)/64 KV steps per block

static __device__ __forceinline__ f32x4 mfma16(bf16x8 a, bf16x8 b, f32x4 c) {
  return __builtin_amdgcn_mfma_f32_16x16x32_bf16(a, b, c, 0, 0, 0);
}
static __device__ __forceinline__ void f2split(float f, unsigned short& hi, unsigned short& lo) {
  __bf16 h = (__bf16)f;
  float rem = f - (float)h;
  __bf16 l = (__bf16)rem;
  hi = __builtin_bit_cast(unsigned short, h);
  lo = __builtin_bit_cast(unsigned short, l);
}

// ---------------------------------------------------------------------------
// Kernel 1: QKV projection. grid (128, 3): x = 64-row tile, y = {Q,K,V}.
// Computes fp32 GEMM X[8192,256] @ W[256,128] via bf16x3 split, writes bf16
// hi/lo outputs. Q pre-scaled by 1/sqrt(128). V written transposed [128][8192].
// ---------------------------------------------------------------------------
__global__ __launch_bounds__(256) void proj_kernel(
    const float* __restrict__ X, const float* __restrict__ Wq,
    const float* __restrict__ Wk, const float* __restrict__ Wv,
    unsigned short* __restrict__ Qh, unsigned short* __restrict__ Ql,
    unsigned short* __restrict__ Kh, unsigned short* __restrict__ Kl,
    unsigned short* __restrict__ VTh, unsigned short* __restrict__ VTl) {
  extern __shared__ char sm[];
  // LDS: Xhi[64][64] 8K | Xlo 8K | Wthi[128][64] 16K | Wtlo 16K = 48K
  const int SXH = 0, SXL = 8192, SWH = 16384, SWL = 32768;

  const int t = threadIdx.x, lane = t & 63, wid = t >> 6;
  const int g = lane >> 4, c = lane & 15;
  const int t0 = blockIdx.x * 64;
  const int y = blockIdx.y;
  const float* W = (y == 0) ? Wq : (y == 1) ? Wk : Wv;

  f32x4 acc[8];
  #pragma unroll
  for (int i = 0; i < 8; ++i) acc[i] = (f32x4){0.f, 0.f, 0.f, 0.f};

  for (int kb = 0; kb < 4; ++kb) {
    const int k0 = kb * 64;
    __syncthreads();
    // stage X chunk [64 rows][64 k] fp32 -> hi/lo LDS (swizzled)
    #pragma unroll
    for (int i = 0; i < 4; ++i) {
      int u = t + 256 * i;            // 0..1023
      int row = u >> 4, c4 = u & 15;  // 16 float4 per row
      float4 xv = *reinterpret_cast<const float4*>(X + (size_t)(t0 + row) * D_INN + k0 + c4 * 4);
      unsigned short h0, h1, h2, h3, l0, l1, l2, l3;
      f2split(xv.x, h0, l0); f2split(xv.y, h1, l1);
      f2split(xv.z, h2, l2); f2split(xv.w, h3, l3);
      uint2 hp, lp2;
      hp.x = (unsigned)h0 | ((unsigned)h1 << 16); hp.y = (unsigned)h2 | ((unsigned)h3 << 16);
      lp2.x = (unsigned)l0 | ((unsigned)l1 << 16); lp2.y = (unsigned)l2 | ((unsigned)l3 << 16);
      int dst = row * 128 + ((c4 * 8) ^ ((row & 7) << 4));
      *reinterpret_cast<uint2*>(sm + SXH + dst) = hp;
      *reinterpret_cast<uint2*>(sm + SXL + dst) = lp2;
    }
    // stage W chunk [64 k][128 c] fp32 -> transposed hi/lo LDS Wt[c][k]
    #pragma unroll
    for (int i = 0; i < 8; ++i) {
      int u = t + 256 * i;            // 0..2047
      int k = u >> 5, c4 = u & 31;    // 32 float4 per k-row
      float4 wv4 = *reinterpret_cast<const float4*>(W + (size_t)(k0 + k) * D_OUTT + c4 * 4);
      float vals[4] = {wv4.x, wv4.y, wv4.z, wv4.w};
      #pragma unroll
      for (int e = 0; e < 4; ++e) {
        int cc = c4 * 4 + e;
        unsigned short h, l;
        f2split(vals[e], h, l);
        int dst = cc * 128 + ((2 * k) ^ ((cc & 7) << 4));
        *reinterpret_cast<unsigned short*>(sm + SWH + dst) = h;
        *reinterpret_cast<unsigned short*>(sm + SWL + dst) = l;
      }
    }
    __syncthreads();
    #pragma unroll
    for (int kc = 0; kc < 2; ++kc) {
      const int kbyte = kc * 64 + g * 16;
      const int arow = wid * 16 + c;
      const int ao = arow * 128 + (kbyte ^ ((arow & 7) << 4));
      bf16x8 ah = *reinterpret_cast<const bf16x8*>(sm + SXH + ao);
      bf16x8 al = *reinterpret_cast<const bf16x8*>(sm + SXL + ao);
      #pragma unroll
      for (int nf = 0; nf < 8; ++nf) {
        int col = c + 16 * nf;
        const int bo = col * 128 + (kbyte ^ ((col & 7) << 4));
        bf16x8 bh = *reinterpret_cast<const bf16x8*>(sm + SWH + bo);
        bf16x8 bl = *reinterpret_cast<const bf16x8*>(sm + SWL + bo);
        acc[nf] = mfma16(ah, bh, acc[nf]);
        acc[nf] = mfma16(ah, bl, acc[nf]);
        acc[nf] = mfma16(al, bh, acc[nf]);
      }
    }
  }
  // epilogue: split fp32 acc into bf16 hi/lo and store
  const float scale = 0.08838834764831845f;  // 1/sqrt(128)
  #pragma unroll
  for (int nf = 0; nf < 8; ++nf) {
    #pragma unroll
    for (int r = 0; r < 4; ++r) {
      float v = acc[nf][r];
      if (y == 0) v *= scale;
      int rt = t0 + wid * 16 + g * 4 + r;  // C-layout row = (l>>4)*4+r
      int cc = c + 16 * nf;                // C-layout col = l&15
      unsigned short h, l;
      f2split(v, h, l);
      if (y == 0)      { Qh[(size_t)rt * 128 + cc] = h; Ql[(size_t)rt * 128 + cc] = l; }
      else if (y == 1) { Kh[(size_t)rt * 128 + cc] = h; Kl[(size_t)rt * 128 + cc] = l; }
      else             { VTh[(size_t)cc * N_TOK + rt] = h; VTl[(size_t)cc * N_TOK + rt] = l; }
    }
  }
}

// ---------------------------------------------------------------------------
// Kernel 2: flash attention, KV-split=4. 512 blocks x 256 threads.
// Block: 64 q-rows (4 waves x 16), 2048 keys in 32 steps of 64.
// bid mapping keeps one KV split per XCD (round-robin dispatch assumption —
// perf heuristic only).
// ---------------------------------------------------------------------------
__global__ __launch_bounds__(256) void attn_kernel(
    const unsigned short* __restrict__ Qh, const unsigned short* __restrict__ Ql,
    const unsigned short* __restrict__ Kh, const unsigned short* __restrict__ Kl,
    const unsigned short* __restrict__ VTh, const unsigned short* __restrict__ VTl,
    float* __restrict__ Op, float* __restrict__ mp, float* __restrict__ lp) {
  extern __shared__ char sm[];
  // LDS: Kh[64][128] 16K | Kl 16K | VTh[128][64] 16K | VTl 16K | P 4x4K = 80K
  const int OKH = 0, OKL = 16384, OVH = 32768, OVL = 49152, OP = 65536;

  const int t = threadIdx.x, lane = t & 63, wid = t >> 6;
  const int g = lane >> 4, c = lane & 15;
  const int bid = blockIdx.x;
  const int split = bid & 3;
  const int qt = (bid >> 3) + 64 * ((bid >> 2) & 1);
  const int q0 = qt * 64;
  const int kv0 = split * 2048;
  const int pbase = OP + wid * 4096;  // per-wave P tile: hi 2K, lo 2K

  // Q fragments in registers (A-layout: row = l&15, k = (l>>4)*8+j)
  bf16x8 qfh[4], qfl[4];
  const int qrow = q0 + wid * 16 + c;
  #pragma unroll
  for (int kc = 0; kc < 4; ++kc) {
    qfh[kc] = *reinterpret_cast<const bf16x8*>(Qh + (size_t)qrow * 128 + kc * 32 + g * 8);
    qfl[kc] = *reinterpret_cast<const bf16x8*>(Ql + (size_t)qrow * 128 + kc * 32 + g * 8);
  }

  f32x4 o[8];
  #pragma unroll
  for (int i = 0; i < 8; ++i) o[i] = (f32x4){0.f, 0.f, 0.f, 0.f};
  float m[4] = {-INFINITY, -INFINITY, -INFINITY, -INFINITY};
  float lsum[4] = {0.f, 0.f, 0.f, 0.f};

  for (int s = 0; s < NSTEP; ++s) {
    const int kb = kv0 + s * 64;
    __syncthreads();  // protect LDS from previous iteration's readers
    // stage K (hi/lo, [64 keys][128 d]) and VT (hi/lo, [128 d][64 keys]), XOR-swizzled
    #pragma unroll
    for (int i = 0; i < 4; ++i) {
      int u = t + 256 * i;             // 0..1023
      int row = u >> 4, c16 = u & 15;  // K: 16 x 16B chunks per 256B row
      int kdst = row * 256 + ((c16 * 16) ^ ((row & 7) << 4));
      *reinterpret_cast<uint4*>(sm + OKH + kdst) =
          *reinterpret_cast<const uint4*>(Kh + (size_t)(kb + row) * 128 + c16 * 8);
      *reinterpret_cast<uint4*>(sm + OKL + kdst) =
          *reinterpret_cast<const uint4*>(Kl + (size_t)(kb + row) * 128 + c16 * 8);
      int d = u >> 3, c8 = u & 7;      // VT: 8 x 16B chunks per 128B row
      int vdst = d * 128 + ((c8 * 16) ^ ((d & 7) << 4));
      *reinterpret_cast<uint4*>(sm + OVH + vdst) =
          *reinterpret_cast<const uint4*>(VTh + (size_t)d * N_TOK + kb + c8 * 8);
      *reinterpret_cast<uint4*>(sm + OVL + vdst) =
          *reinterpret_cast<const uint4*>(VTl + (size_t)d * N_TOK + kb + c8 * 8);
    }
    __syncthreads();

    // S = Qs @ K^T (split-3). C-layout: row q = 4g+r, col key = c+16nf.
    f32x4 sc[4];
    #pragma unroll
    for (int i = 0; i < 4; ++i) sc[i] = (f32x4){0.f, 0.f, 0.f, 0.f};
    #pragma unroll
    for (int kc = 0; kc < 4; ++kc) {
      const int kbyte = kc * 64 + g * 16;
      #pragma unroll
      for (int nf = 0; nf < 4; ++nf) {
        int key = c + 16 * nf;
        const int bo = key * 256 + (kbyte ^ ((key & 7) << 4));
        bf16x8 bh = *reinterpret_cast<const bf16x8*>(sm + OKH + bo);
        bf16x8 bl = *reinterpret_cast<const bf16x8*>(sm + OKL + bo);
        sc[nf] = mfma16(qfh[kc], bh, sc[nf]);
        sc[nf] = mfma16(qfh[kc], bl, sc[nf]);
        sc[nf] = mfma16(qfl[kc], bh, sc[nf]);
      }
    }

    // online softmax (rows distributed: lane group g holds rows 4g..4g+3)
    float al[4], ps[4];
    #pragma unroll
    for (int r = 0; r < 4; ++r) {
      float v = fmaxf(fmaxf(sc[0][r], sc[1][r]), fmaxf(sc[2][r], sc[3][r]));
      #pragma unroll
      for (int off = 1; off < 16; off <<= 1) v = fmaxf(v, __shfl_xor(v, off));
      float mn = fmaxf(m[r], v);
      al[r] = __expf(m[r] - mn);
      m[r] = mn;
      ps[r] = 0.f;
    }
    // P = exp(S-m), split to bf16 hi/lo, store to per-wave LDS (A-layout source)
    #pragma unroll
    for (int nf = 0; nf < 4; ++nf) {
      #pragma unroll
      for (int r = 0; r < 4; ++r) {
        float p = __expf(sc[nf][r] - m[r]);
        ps[r] += p;
        int qr = g * 4 + r;
        int key = c + 16 * nf;
        int pb = qr * 128 + ((2 * key) ^ ((qr & 7) << 4));
        unsigned short h, l;
        f2split(p, h, l);
        *reinterpret_cast<unsigned short*>(sm + pbase + pb) = h;
        *reinterpret_cast<unsigned short*>(sm + pbase + 2048 + pb) = l;
      }
    }
    #pragma unroll
    for (int r = 0; r < 4; ++r) lsum[r] = lsum[r] * al[r] + ps[r];
    f32x4 av = {al[0], al[1], al[2], al[3]};
    #pragma unroll
    for (int i = 0; i < 8; ++i) o[i] *= av;

    // O += P @ V (split-3). A = P from LDS (row q = l&15, k = keys),
    // B = V^T tile (k = keys contiguous, col d = l&15 + 16nf).
    #pragma unroll
    for (int kc2 = 0; kc2 < 2; ++kc2) {
      const int kbyte = kc2 * 64 + g * 16;
      const int ab = c * 128 + (kbyte ^ ((c & 7) << 4));
      bf16x8 pah = *reinterpret_cast<const bf16x8*>(sm + pbase + ab);
      bf16x8 pal = *reinterpret_cast<const bf16x8*>(sm + pbase + 2048 + ab);
      #pragma unroll
      for (int nf = 0; nf < 8; ++nf) {
        int d = c + 16 * nf;
        const int bo = d * 128 + (kbyte ^ ((d & 7) << 4));
        bf16x8 vh = *reinterpret_cast<const bf16x8*>(sm + OVH + bo);
        bf16x8 vl = *reinterpret_cast<const bf16x8*>(sm + OVL + bo);
        o[nf] = mfma16(pah, vh, o[nf]);
        o[nf] = mfma16(pah, vl, o[nf]);
        o[nf] = mfma16(pal, vh, o[nf]);
      }
    }
  }

  // full row-sum of l across the 16 lanes of each group
  #pragma unroll
  for (int r = 0; r < 4; ++r) {
    float v = lsum[r];
    #pragma unroll
    for (int off = 1; off < 16; off <<= 1) v += __shfl_xor(v, off);
    lsum[r] = v;
  }
  // store unnormalized partial O + (m, l)
  #pragma unroll
  for (int nf = 0; nf < 8; ++nf) {
    #pragma unroll
    for (int r = 0; r < 4; ++r) {
      size_t rt = (size_t)(q0 + wid * 16 + g * 4 + r);
      Op[(size_t)split * N_TOK * 128 + rt * 128 + c + 16 * nf] = o[nf][r];
    }
  }
  if (c == 0) {
    #pragma unroll
    for (int r = 0; r < 4; ++r) {
      int rt = q0 + wid * 16 + g * 4 + r;
      mp[split * N_TOK + rt] = m[r];
      lp[split * N_TOK + rt] = lsum[r];
    }
  }
}

// ---------------------------------------------------------------------------
// Kernel 3: merge the 4 KV-split partials. One thread per 4 output floats.
// ---------------------------------------------------------------------------
__global__ __launch_bounds__(256) void merge_kernel(
    const float* __restrict__ Op, const float* __restrict__ mp,
    const float* __restrict__ lp, float* __restrict__ out) {
  int idx = blockIdx.x * 256 + threadIdx.x;  // 0 .. 8192*32-1
  int row = idx >> 5, d4 = (idx & 31) * 4;
  float mm[NSPLIT], ll[NSPLIT];
  #pragma unroll
  for (int s = 0; s < NSPLIT; ++s) {
    mm[s] = mp[s * N_TOK + row];
    ll[s] = lp[s * N_TOK + row];
  }
  float M = fmaxf(fmaxf(mm[0], mm[1]), fmaxf(mm[2], mm[3]));
  float L = 0.f, ww[NSPLIT];
  #pragma unroll
  for (int s = 0; s < NSPLIT; ++s) { ww[s] = __expf(mm[s] - M); L += ww[s] * ll[s]; }
  f32x4 a = (f32x4){0.f, 0.f, 0.f, 0.f};
  #pragma unroll
  for (int s = 0; s < NSPLIT; ++s) {
    f32x4 v = *reinterpret_cast<const f32x4*>(Op + (size_t)s * N_TOK * 128 + (size_t)row * 128 + d4);
    a += v * ww[s];
  }
  f32x4 res = a * (1.0f / L);
  *reinterpret_cast<f32x4*>(out + (size_t)row * 128 + d4) = res;
}

// ---------------------------------------------------------------------------
extern "C" void kernel_launch(void* const* d_in, const int* in_sizes, int n_in,
                              void* d_out, int out_size, void* d_ws, size_t ws_size,
                              hipStream_t stream) {
  (void)in_sizes; (void)n_in; (void)out_size; (void)ws_size;
  const float* X  = (const float*)d_in[0];
  const float* Wq = (const float*)d_in[1];
  const float* Wk = (const float*)d_in[2];
  const float* Wv = (const float*)d_in[3];
  float* out = (float*)d_out;
  char* ws = (char*)d_ws;

  const size_t SZ = (size_t)N_TOK * 128 * sizeof(unsigned short);  // 2 MB
  unsigned short* Qh  = (unsigned short*)(ws + 0 * SZ);
  unsigned short* Ql  = (unsigned short*)(ws + 1 * SZ);
  unsigned short* Kh  = (unsigned short*)(ws + 2 * SZ);
  unsigned short* Kl  = (unsigned short*)(ws + 3 * SZ);
  unsigned short* VTh = (unsigned short*)(ws + 4 * SZ);
  unsigned short* VTl = (unsigned short*)(ws + 5 * SZ);
  float* Op = (float*)(ws + 6 * SZ);                               // 4 x 4 MB
  float* mp = (float*)(ws + 6 * SZ + (size_t)NSPLIT * N_TOK * 128 * sizeof(float));
  float* lp = mp + NSPLIT * N_TOK;

  // defensive: allow >64KB dynamic LDS (no-op if already permitted)
  (void)hipFuncSetAttribute((const void*)proj_kernel,
                            hipFuncAttributeMaxDynamicSharedMemorySize, 49152);
  (void)hipFuncSetAttribute((const void*)attn_kernel,
                            hipFuncAttributeMaxDynamicSharedMemorySize, 81920);

  proj_kernel<<<dim3(128, 3), 256, 49152, stream>>>(X, Wq, Wk, Wv, Qh, Ql, Kh, Kl, VTh, VTl);
  attn_kernel<<<512, 256, 81920, stream>>>(Qh, Ql, Kh, Kl, VTh, VTl, Op, mp, lp);
  merge_kernel<<<1024, 256, 0, stream>>>(Op, mp, lp, out);
}

// Round 3
// 168.403 us; speedup vs baseline: 1.4662x; 1.4662x over previous
//
#include <hip/hip_runtime.h>
#include <math.h>

// Self-attention N=8192, D_in=256, D_out=128, fp32 in/out.
// fp32 accuracy via bf16 hi/lo split (3 MFMAs for QK^T, 2 for PV; P bf16-only).
// Structure: prep (split X/W) -> proj (bf16 GEMM, gload_lds staged) ->
// flash attn (32x32 MFMA, swapped QK^T, in-register softmax + permlane32_swap
// P re-layout, KV-split=8) -> merge.
// ws: [Qh Ql Kh Kl VTh VTl 12MB][mp lp 0.5MB][Op 32MB (aliases Xh/Xl/WT, dead by attn)]

typedef float f32x4 __attribute__((ext_vector_type(4)));
typedef float f32x16 __attribute__((ext_vector_type(16)));
typedef __bf16 bf16x8 __attribute__((ext_vector_type(8)));
typedef unsigned short ushort_t;
typedef ushort_t us4 __attribute__((ext_vector_type(4)));
typedef unsigned u32x2 __attribute__((ext_vector_type(2)));

#define N_TOK 8192
#define NSPLIT 8
#define NSTEP 16  // 8192/8/64

static __device__ __forceinline__ f32x16 mfma32(bf16x8 a, bf16x8 b, f32x16 c) {
  return __builtin_amdgcn_mfma_f32_32x32x16_bf16(a, b, c, 0, 0, 0);
}
static __device__ __forceinline__ void f2split(float f, ushort_t& hi, ushort_t& lo) {
  __bf16 h = (__bf16)f;
  float rem = f - (float)h;
  __bf16 l2 = (__bf16)rem;
  hi = __builtin_bit_cast(ushort_t, h);
  lo = __builtin_bit_cast(ushort_t, l2);
}
static __device__ __forceinline__ void gload16(const void* g, void* l) {
  __builtin_amdgcn_global_load_lds(
      (const __attribute__((address_space(1))) unsigned*)g,
      (__attribute__((address_space(3))) unsigned*)l, 16, 0, 0);
}
static __device__ __forceinline__ unsigned cvtpk(float lo, float hi) {
  unsigned w;
  asm("v_cvt_pk_bf16_f32 %0, %1, %2" : "=v"(w) : "v"(lo), "v"(hi));
  return w;
}

// ---------------------------------------------------------------------------
// Kernel 0: split X (float4-vectorized) and W (transposed) into bf16 hi/lo.
// ---------------------------------------------------------------------------
__global__ __launch_bounds__(256) void prep_kernel(
    const float* __restrict__ X, const float* __restrict__ Wq,
    const float* __restrict__ Wk, const float* __restrict__ Wv,
    ushort_t* __restrict__ Xh, ushort_t* __restrict__ Xl,
    ushort_t* __restrict__ WTh, ushort_t* __restrict__ WTl) {
  int gid = blockIdx.x * 256 + threadIdx.x;
  if (gid < 524288) {  // 8192*256/4 float4s
    float4 v = reinterpret_cast<const float4*>(X)[gid];
    us4 h, l;
    ushort_t hh, ll;
    f2split(v.x, hh, ll); h[0] = hh; l[0] = ll;
    f2split(v.y, hh, ll); h[1] = hh; l[1] = ll;
    f2split(v.z, hh, ll); h[2] = hh; l[2] = ll;
    f2split(v.w, hh, ll); h[3] = hh; l[3] = ll;
    reinterpret_cast<us4*>(Xh)[gid] = h;
    reinterpret_cast<us4*>(Xl)[gid] = l;
  } else if (gid < 524288 + 98304) {
    int e = gid - 524288;
    int y = e >> 15, r = e & 32767;
    int k = r >> 7, c = r & 127;
    const float* W = (y == 0) ? Wq : (y == 1) ? Wk : Wv;
    ushort_t h, l;
    f2split(W[r], h, l);
    WTh[y * 32768 + c * 256 + k] = h;  // WT[y][c][k]
    WTl[y * 32768 + c * 256 + k] = l;
  }
}

// ---------------------------------------------------------------------------
// Kernel 1: QKV projection, 32x32x16 MFMA, split-3. grid (128, 3).
// Block: 64 tokens x 128 dout; 4 waves (2 row x 2 col). K sliced by 64.
// Q pre-scaled by (1/sqrt(128))*log2(e). V written transposed via LDS.
// ---------------------------------------------------------------------------
__global__ __launch_bounds__(256) void proj_kernel(
    const ushort_t* __restrict__ Xh, const ushort_t* __restrict__ Xl,
    const ushort_t* __restrict__ WTh, const ushort_t* __restrict__ WTl,
    ushort_t* __restrict__ Qh, ushort_t* __restrict__ Ql,
    ushort_t* __restrict__ Kh, ushort_t* __restrict__ Kl,
    ushort_t* __restrict__ VTh, ushort_t* __restrict__ VTl) {
  __shared__ __align__(16) char sm[49152];
  const int SXH = 0, SXL = 8192, SWH = 16384, SWL = 32768;
  int t = threadIdx.x, l = t & 63, wid = t >> 6;
  int c32 = l & 31, h = l >> 5;
  int wr = wid >> 1, wc = wid & 1;
  int t0 = blockIdx.x * 64, y = blockIdx.y;
  const ushort_t* WThy = WTh + y * 32768;
  const ushort_t* WTly = WTl + y * 32768;

  f32x16 zero = {};
  f32x16 acc[2];
  acc[0] = zero; acc[1] = zero;

  for (int sl = 0; sl < 4; ++sl) {
    int k0 = sl * 64;
    __syncthreads();
    // stage: Xh 8 chunks, Xl 8, WTh 16, WTl 16 (1KB each); 12 per wave.
    #pragma unroll
    for (int j = 0; j < 12; ++j) {
      int id = wid * 12 + j;
      const ushort_t* src;
      char* dst;
      if (id < 16) {
        const ushort_t* base = (id < 8) ? Xh : Xl;
        int c_ = id & 7;
        int row = 8 * c_ + (l >> 3);
        int slot = l & 7;
        src = base + (size_t)(t0 + row) * 256 + k0 + ((slot ^ (row & 7)) * 8);
        dst = sm + ((id < 8) ? SXH : SXL) + c_ * 1024 + l * 16;
      } else {
        const ushort_t* base = (id < 32) ? WThy : WTly;
        int c_ = (id - 16) & 15;
        int row = 8 * c_ + (l >> 3);
        int slot = l & 7;
        src = base + (size_t)row * 256 + k0 + ((slot ^ (row & 7)) * 8);
        dst = sm + ((id < 32) ? SWH : SWL) + c_ * 1024 + l * 16;
      }
      gload16(src, dst);
    }
    asm volatile("s_waitcnt vmcnt(0)" ::: "memory");
    __syncthreads();
    #pragma unroll
    for (int ks = 0; ks < 4; ++ks) {
      int ar = 32 * wr + c32;
      int ao = ar * 128 + (((2 * ks + h) ^ (ar & 7)) * 16);
      bf16x8 ah = *(const bf16x8*)(sm + SXH + ao);
      bf16x8 axl = *(const bf16x8*)(sm + SXL + ao);
      #pragma unroll
      for (int ct = 0; ct < 2; ++ct) {
        int bc = 64 * wc + 32 * ct + c32;
        int bo = bc * 128 + (((2 * ks + h) ^ (bc & 7)) * 16);
        bf16x8 bh = *(const bf16x8*)(sm + SWH + bo);
        bf16x8 bl2 = *(const bf16x8*)(sm + SWL + bo);
        acc[ct] = mfma32(ah, bh, acc[ct]);
        acc[ct] = mfma32(ah, bl2, acc[ct]);
        acc[ct] = mfma32(axl, bh, acc[ct]);
      }
    }
  }

  const float QS = 0.12751744f;  // (1/sqrt(128)) * log2(e)
  if (y < 2) {
    ushort_t* Hh = y ? Kh : Qh;
    ushort_t* Hl = y ? Kl : Ql;
    #pragma unroll
    for (int ct = 0; ct < 2; ++ct)
      #pragma unroll
      for (int r = 0; r < 16; ++r) {
        float v = acc[ct][r];
        if (y == 0) v *= QS;
        int rt = t0 + 32 * wr + (r & 3) + 8 * (r >> 2) + 4 * h;
        int cc = 64 * wc + 32 * ct + c32;
        ushort_t hh, ll;
        f2split(v, hh, ll);
        Hh[(size_t)rt * 128 + cc] = hh;
        Hl[(size_t)rt * 128 + cc] = ll;
      }
  } else {
    // V: transpose via LDS, write VT[128][8192] hi/lo coalesced.
    __syncthreads();
    #pragma unroll
    for (int ct = 0; ct < 2; ++ct)
      #pragma unroll
      for (int r = 0; r < 16; ++r) {
        float v = acc[ct][r];
        int rtl = 32 * wr + (r & 3) + 8 * (r >> 2) + 4 * h;
        int cc = 64 * wc + 32 * ct + c32;
        ushort_t hh, ll;
        f2split(v, hh, ll);
        *(ushort_t*)(sm + rtl * 272 + cc * 2) = hh;
        *(ushort_t*)(sm + 17408 + rtl * 272 + cc * 2) = ll;
      }
    __syncthreads();
    int cc = t >> 1, hs = t & 1;
    #pragma unroll
    for (int jj = 0; jj < 4; ++jj) {
      int r0 = hs * 32 + jj * 8;
      us4 a, b, a2, b2;
      #pragma unroll
      for (int e = 0; e < 4; ++e) {
        a[e]  = *(const ushort_t*)(sm + (r0 + e) * 272 + cc * 2);
        b[e]  = *(const ushort_t*)(sm + (r0 + 4 + e) * 272 + cc * 2);
        a2[e] = *(const ushort_t*)(sm + 17408 + (r0 + e) * 272 + cc * 2);
        b2[e] = *(const ushort_t*)(sm + 17408 + (r0 + 4 + e) * 272 + cc * 2);
      }
      *(us4*)(VTh + (size_t)cc * N_TOK + t0 + r0) = a;
      *(us4*)(VTh + (size_t)cc * N_TOK + t0 + r0 + 4) = b;
      *(us4*)(VTl + (size_t)cc * N_TOK + t0 + r0) = a2;
      *(us4*)(VTl + (size_t)cc * N_TOK + t0 + r0 + 4) = b2;
    }
  }
}

// ---------------------------------------------------------------------------
// Kernel 2: flash attention. 512 blocks x 256 threads, KV-split=8 (bid&7 ->
// one split per XCD). Block: 128 q (4 waves x 32), 16 steps of 64 keys.
// Swapped QK^T (S^T = K*Q^T) -> per-lane scalar softmax state -> in-register
// P via cvt_pk + permlane32_swap -> O^T = V^T * P^T. LDS 64KB, 2 blocks/CU.
// ---------------------------------------------------------------------------
__global__ __launch_bounds__(256, 2) void attn_kernel(
    const ushort_t* __restrict__ Qh, const ushort_t* __restrict__ Ql,
    const ushort_t* __restrict__ Kh, const ushort_t* __restrict__ Kl,
    const ushort_t* __restrict__ VTh, const ushort_t* __restrict__ VTl,
    float* __restrict__ Op, float* __restrict__ mp, float* __restrict__ lp) {
  extern __shared__ __align__(16) char sm[];
  const int OKH = 0, OKL = 16384, OVH = 32768, OVL = 49152;
  int t = threadIdx.x, l = t & 63, wid = t >> 6;
  int c32 = l & 31, h = l >> 5;
  int bid = blockIdx.x;
  int split = bid & 7, qt = bid >> 3;
  int qb = qt * 128, kv0 = split * 1024;
  int q_lane = qb + wid * 32 + c32;

  // Q fragments (B-operand: lane holds Q[q=l&31-own][d = 16ks + 8h + j])
  bf16x8 qfh[8], qfl[8];
  #pragma unroll
  for (int ks = 0; ks < 8; ++ks) {
    qfh[ks] = *(const bf16x8*)(Qh + (size_t)q_lane * 128 + ks * 16 + h * 8);
    qfl[ks] = *(const bf16x8*)(Ql + (size_t)q_lane * 128 + ks * 16 + h * 8);
  }

  f32x16 zero = {};
  f32x16 od[4];
  #pragma unroll
  for (int dt = 0; dt < 4; ++dt) od[dt] = zero;
  float m = -INFINITY, lsum = 0.f;

  for (int s = 0; s < NSTEP; ++s) {
    int kb = kv0 + s * 64;
    __syncthreads();
    // stage K hi/lo [64][128] and VT hi/lo [128][64] (64 x 1KB chunks),
    // linear LDS dest + inverse-swizzled global source (rule 21).
    #pragma unroll
    for (int j = 0; j < 16; ++j) {
      int id = wid * 16 + j;
      const ushort_t* src;
      char* dst;
      if (id < 32) {
        const ushort_t* base = (id < 16) ? Kh : Kl;
        int c_ = id & 15;
        int row = 4 * c_ + (l >> 4);
        int slot = l & 15;
        src = base + (size_t)(kb + row) * 128 + ((slot ^ (row & 15)) * 8);
        dst = sm + ((id < 16) ? OKH : OKL) + c_ * 1024 + l * 16;
      } else {
        const ushort_t* base = (id < 48) ? VTh : VTl;
        int c_ = id & 15;
        int d = 8 * c_ + (l >> 3);
        int slot = l & 7;
        src = base + (size_t)d * N_TOK + kb + ((slot ^ (d & 7)) * 8);
        dst = sm + ((id < 48) ? OVH : OVL) + c_ * 1024 + l * 16;
      }
      gload16(src, dst);
    }
    asm volatile("s_waitcnt vmcnt(0)" ::: "memory");
    __syncthreads();

    // S^T = K * Q^T (split-3): sc0 = keys 0..31, sc1 = keys 32..63; col = q.
    f32x16 sc0 = zero, sc1 = zero;
    #pragma unroll
    for (int ks = 0; ks < 8; ++ks) {
      int so = ((2 * ks + h) ^ (c32 & 15)) * 16;
      bf16x8 a0h = *(const bf16x8*)(sm + OKH + c32 * 256 + so);
      bf16x8 a0l = *(const bf16x8*)(sm + OKL + c32 * 256 + so);
      bf16x8 a1h = *(const bf16x8*)(sm + OKH + 8192 + c32 * 256 + so);
      bf16x8 a1l = *(const bf16x8*)(sm + OKL + 8192 + c32 * 256 + so);
      sc0 = mfma32(a0h, qfh[ks], sc0);
      sc0 = mfma32(a0h, qfl[ks], sc0);
      sc0 = mfma32(a0l, qfh[ks], sc0);
      sc1 = mfma32(a1h, qfh[ks], sc1);
      sc1 = mfma32(a1h, qfl[ks], sc1);
      sc1 = mfma32(a1l, qfh[ks], sc1);
    }

    // online softmax, log2 units (log2e folded into Q scale). One q per lane.
    float pm = sc0[0];
    #pragma unroll
    for (int r = 1; r < 16; ++r) pm = fmaxf(pm, sc0[r]);
    #pragma unroll
    for (int r = 0; r < 16; ++r) pm = fmaxf(pm, sc1[r]);
    pm = fmaxf(pm, __shfl_xor(pm, 32));
    float mn = fmaxf(m, pm);
    float al = exp2f(m - mn);
    m = mn;
    float ps = 0.f;
    #pragma unroll
    for (int r = 0; r < 16; ++r) { sc0[r] = exp2f(sc0[r] - m); ps += sc0[r]; }
    #pragma unroll
    for (int r = 0; r < 16; ++r) { sc1[r] = exp2f(sc1[r] - m); ps += sc1[r]; }
    lsum = lsum * al + ps;
    #pragma unroll
    for (int dt = 0; dt < 4; ++dt) od[dt] *= al;

    // P^T B-fragments in-register: 16 cvt_pk + 8 permlane32_swap.
    bf16x8 pf[4];
    #pragma unroll
    for (int ks = 0; ks < 4; ++ks) {
      const f32x16& P = (ks < 2) ? sc0 : sc1;
      int r0 = 8 * (ks & 1);
      unsigned A0 = cvtpk(P[r0 + 0], P[r0 + 1]);
      unsigned A1 = cvtpk(P[r0 + 2], P[r0 + 3]);
      unsigned B0 = cvtpk(P[r0 + 4], P[r0 + 5]);
      unsigned B1 = cvtpk(P[r0 + 6], P[r0 + 7]);
      u32x2 s0 = __builtin_amdgcn_permlane32_swap(A0, B0, false, false);
      u32x2 s1 = __builtin_amdgcn_permlane32_swap(A1, B1, false, false);
      union { unsigned u[4]; bf16x8 v; } cvt;
      cvt.u[0] = s0[0]; cvt.u[1] = s1[0]; cvt.u[2] = s0[1]; cvt.u[3] = s1[1];
      pf[ks] = cvt.v;
    }

    // O^T += V^T * P^T (V hi/lo, P bf16)
    #pragma unroll
    for (int ks = 0; ks < 4; ++ks) {
      #pragma unroll
      for (int dt = 0; dt < 4; ++dt) {
        int row = 32 * dt + c32;
        int so2 = row * 128 + (((2 * ks + h) ^ (c32 & 7)) * 16);
        bf16x8 vh = *(const bf16x8*)(sm + OVH + so2);
        bf16x8 vl2 = *(const bf16x8*)(sm + OVL + so2);
        od[dt] = mfma32(vh, pf[ks], od[dt]);
        od[dt] = mfma32(vl2, pf[ks], od[dt]);
      }
    }
  }

  lsum += __shfl_xor(lsum, 32);
  // store O^T partial: Op[split][d][q] (coalesced along q)
  #pragma unroll
  for (int dt = 0; dt < 4; ++dt)
    #pragma unroll
    for (int r = 0; r < 16; ++r) {
      int d = 32 * dt + (r & 3) + 8 * (r >> 2) + 4 * h;
      Op[(size_t)(split * 128 + d) * N_TOK + q_lane] = od[dt][r];
    }
  if (h == 0) {
    mp[split * N_TOK + q_lane] = m;
    lp[split * N_TOK + q_lane] = lsum;
  }
}

// ---------------------------------------------------------------------------
// Kernel 3: merge 8 partials. Block = 32 q x 128 d, LDS transpose so both
// Op reads (along q) and out writes (along d) are coalesced.
// ---------------------------------------------------------------------------
__global__ __launch_bounds__(256) void merge_kernel(
    const float* __restrict__ Op, const float* __restrict__ mp,
    const float* __restrict__ lp, float* __restrict__ out) {
  __shared__ float accs[32][129];
  __shared__ float Ls[32];
  int t = threadIdx.x;
  int q0 = blockIdx.x * 32;
  int ql = t & 31, dr = t >> 5;
  float mm[NSPLIT], ll[NSPLIT];
  #pragma unroll
  for (int s2 = 0; s2 < NSPLIT; ++s2) {
    mm[s2] = mp[s2 * N_TOK + q0 + ql];
    ll[s2] = lp[s2 * N_TOK + q0 + ql];
  }
  float M = mm[0];
  #pragma unroll
  for (int s2 = 1; s2 < NSPLIT; ++s2) M = fmaxf(M, mm[s2]);
  float w[NSPLIT], L = 0.f;
  #pragma unroll
  for (int s2 = 0; s2 < NSPLIT; ++s2) { w[s2] = exp2f(mm[s2] - M); L += w[s2] * ll[s2]; }
  if (dr == 0) Ls[ql] = L;
  for (int dd = dr; dd < 128; dd += 8) {
    float a = 0.f;
    #pragma unroll
    for (int s2 = 0; s2 < NSPLIT; ++s2)
      a += w[s2] * Op[(size_t)(s2 * 128 + dd) * N_TOK + q0 + ql];
    accs[ql][dd] = a;
  }
  __syncthreads();
  int q = t >> 3, db = (t & 7) * 16;
  float inv = 1.0f / Ls[q];
  #pragma unroll
  for (int jj = 0; jj < 4; ++jj) {
    f32x4 v;
    #pragma unroll
    for (int e = 0; e < 4; ++e) v[e] = accs[q][db + jj * 4 + e] * inv;
    *reinterpret_cast<f32x4*>(out + (size_t)(q0 + q) * 128 + db + jj * 4) = v;
  }
}

// ---------------------------------------------------------------------------
extern "C" void kernel_launch(void* const* d_in, const int* in_sizes, int n_in,
                              void* d_out, int out_size, void* d_ws, size_t ws_size,
                              hipStream_t stream) {
  (void)in_sizes; (void)n_in; (void)out_size; (void)ws_size;
  const float* X  = (const float*)d_in[0];
  const float* Wq = (const float*)d_in[1];
  const float* Wk = (const float*)d_in[2];
  const float* Wv = (const float*)d_in[3];
  float* out = (float*)d_out;
  char* ws = (char*)d_ws;

  const size_t MB = 1048576;
  ushort_t* Qh  = (ushort_t*)(ws + 0 * MB);
  ushort_t* Ql  = (ushort_t*)(ws + 2 * MB);
  ushort_t* Kh  = (ushort_t*)(ws + 4 * MB);
  ushort_t* Kl  = (ushort_t*)(ws + 6 * MB);
  ushort_t* VTh = (ushort_t*)(ws + 8 * MB);
  ushort_t* VTl = (ushort_t*)(ws + 10 * MB);
  float* mpp = (float*)(ws + 12 * MB);
  float* lpp = (float*)(ws + 12 * MB + 262144);
  float* Op  = (float*)(ws + 12 * MB + 524288);   // 32 MB
  // prep-only region, aliased inside Op (dead before attn writes Op):
  ushort_t* Xh  = (ushort_t*)(ws + 12 * MB + 524288);
  ushort_t* Xl  = (ushort_t*)(ws + 16 * MB + 524288);
  ushort_t* WTh = (ushort_t*)(ws + 20 * MB + 524288);
  ushort_t* WTl = (ushort_t*)(ws + 20 * MB + 524288 + 196608);

  (void)hipFuncSetAttribute((const void*)attn_kernel,
                            hipFuncAttributeMaxDynamicSharedMemorySize, 65536);

  prep_kernel<<<2432, 256, 0, stream>>>(X, Wq, Wk, Wv, Xh, Xl, WTh, WTl);
  proj_kernel<<<dim3(128, 3), 256, 0, stream>>>(Xh, Xl, WTh, WTl,
                                                Qh, Ql, Kh, Kl, VTh, VTl);
  attn_kernel<<<512, 256, 65536, stream>>>(Qh, Ql, Kh, Kl, VTh, VTl, Op, mpp, lpp);
  merge_kernel<<<256, 256, 0, stream>>>(Op, mpp, lpp, out);
}